// Round 1
// baseline (189.529 us; speedup 1.0000x reference)
//
#include <hip/hip_runtime.h>

// Problem constants (static shapes from reference)
#define B 64
#define C 2048
#define H 24
#define W 8
#define HW (H * W)            // 192 spatial positions per (b,c)
#define CHUNKS 16             // channel chunks per batch for parallelism
#define CPC (C / CHUNKS)      // 128 channels per chunk
#define RH 8                  // round(0.33 * 24) = 8 rows zeroed
#define CHW4 ((C * HW) / 4)   // float4s per batch = 98304

// ---------------------------------------------------------------------------
// Kernel 1: partial sum of squares over a channel chunk.
// grid = B*CHUNKS blocks, block = HW (192) threads = 3 waves.
// Thread t handles spatial position t; each c-iteration the block reads
// 192 contiguous floats (768 B) -> fully coalesced.
// partial[(b*CHUNKS + chunk)*HW + t] = sum over chunk's channels of x^2.
// ---------------------------------------------------------------------------
__global__ void k_ss(const float* __restrict__ x, float* __restrict__ partial) {
    const int blk = blockIdx.x;
    const int b = blk / CHUNKS;
    const int chunk = blk % CHUNKS;
    const int t = threadIdx.x;  // 0..191

    const float* p = x + (size_t)b * C * HW + (size_t)chunk * CPC * HW + t;
    float acc0 = 0.f, acc1 = 0.f, acc2 = 0.f, acc3 = 0.f;
    #pragma unroll
    for (int j = 0; j < CPC; j += 4) {
        float v0 = p[(size_t)(j + 0) * HW];
        float v1 = p[(size_t)(j + 1) * HW];
        float v2 = p[(size_t)(j + 2) * HW];
        float v3 = p[(size_t)(j + 3) * HW];
        acc0 += v0 * v0;
        acc1 += v1 * v1;
        acc2 += v2 * v2;
        acc3 += v3 * v3;
    }
    partial[(size_t)blk * HW + t] = (acc0 + acc1) + (acc2 + acc3);
}

// ---------------------------------------------------------------------------
// Kernel 2: reduce partials -> per-spatial sumsq -> per-row max over w ->
// rank rows, zero top-RH. grid = B blocks, block = HW (192) threads.
// Tie-break (o == my && h > t) matches stable ascending argsort taking the
// LAST rh entries (larger index wins ties).
// ---------------------------------------------------------------------------
__global__ void k_mask(const float* __restrict__ partial, float* __restrict__ mask) {
    __shared__ float sm[HW];
    __shared__ float rs[H];
    const int b = blockIdx.x;
    const int t = threadIdx.x;

    float s = 0.f;
    #pragma unroll
    for (int ch = 0; ch < CHUNKS; ++ch)
        s += partial[((size_t)b * CHUNKS + ch) * HW + t];
    sm[t] = s;
    __syncthreads();

    if (t < H) {
        float m = sm[t * W];
        #pragma unroll
        for (int w = 1; w < W; ++w) m = fmaxf(m, sm[t * W + w]);
        rs[t] = m;
    }
    __syncthreads();

    if (t < H) {
        const float my = rs[t];
        int cnt = 0;
        #pragma unroll
        for (int h = 0; h < H; ++h) {
            const float o = rs[h];
            if (o > my || (o == my && h > t)) ++cnt;
        }
        mask[b * H + t] = (cnt < RH) ? 0.0f : 1.0f;
    }
}

// ---------------------------------------------------------------------------
// Kernel 3: out = x * mask[b,h], float4 vectorized (16 B/lane, coalesced).
// grid = (CHW4/256, B), block = 256. Each h-row is exactly 2 float4s, so
// h = (idx4 >> 1) % H.
// ---------------------------------------------------------------------------
__global__ void k_apply(const float* __restrict__ x, const float* __restrict__ mask,
                        float* __restrict__ out) {
    const int b = blockIdx.y;
    const int idx4 = blockIdx.x * blockDim.x + threadIdx.x;  // float4 idx in batch
    const int h = (idx4 >> 1) % H;
    const float m = mask[b * H + h];
    const size_t e = (size_t)b * (C * HW) + (size_t)idx4 * 4;
    const float4 v = *(const float4*)(x + e);
    float4 r;
    r.x = v.x * m; r.y = v.y * m; r.z = v.z * m; r.w = v.w * m;
    *(float4*)(out + e) = r;
}

// ---------------------------------------------------------------------------
extern "C" void kernel_launch(void* const* d_in, const int* in_sizes, int n_in,
                              void* d_out, int out_size, void* d_ws, size_t ws_size,
                              hipStream_t stream) {
    const float* x = (const float*)d_in[0];
    float* out = (float*)d_out;
    float* partial = (float*)d_ws;                  // B*CHUNKS*HW floats (768 KB)
    float* mask = partial + (size_t)B * CHUNKS * HW; // B*H floats

    k_ss<<<B * CHUNKS, HW, 0, stream>>>(x, partial);
    k_mask<<<B, HW, 0, stream>>>(partial, mask);
    k_apply<<<dim3(CHW4 / 256, B), 256, 0, stream>>>(x, mask, out);
}